// Round 1
// 213.772 us; speedup vs baseline: 1.0293x; 1.0293x over previous
//
#include <hip/hip_runtime.h>

#define B_   32
#define S_   2048
#define D_   512
#define H_   32
#define BS_  (B_*S_)
#define INV_SCALE 0.17677669529663689f   // 1/sqrt(32)

// workspace layout (bytes):
// [0, 32768):            PTbf    ushort[32][512]   bf16 transposed projector
// [32768, 49152):        zdm     float2[2048]      per-block (Z, DM) partials
// [49152, 4243456):      partial float[2048][512]  per-block numerator partials

typedef short  s16x8 __attribute__((ext_vector_type(8)));
typedef float  f32x4 __attribute__((ext_vector_type(4)));

__device__ __forceinline__ float sigmoidf_(float x) {
    return 1.0f / (1.0f + __expf(-x));
}

__device__ __forceinline__ unsigned short f2bf(float f) {
    unsigned u = __float_as_uint(f);
    u += 0x7fffu + ((u >> 16) & 1u);     // round-to-nearest-even
    return (unsigned short)(u >> 16);
}

// ---------------- transpose projector to bf16: PTbf[j][d] = bf16(P[d][j]) ----
__global__ void kTransposeBf(const float* __restrict__ P, unsigned short* __restrict__ PTbf) {
    int o = blockIdx.x * 256 + threadIdx.x;      // 16384 total
    int j = o >> 9, d = o & 511;
    PTbf[o] = f2bf(P[d * H_ + j]);
}

// ---- fused scores + unnormalized weighted partial sum: 32 rows/block ----
#define XST 520                               // bf16 row stride in LDS (512 + 8 pad)
#define WST 36                                // w0f row stride (floats), 16B-aligned rows

__global__ __launch_bounds__(256, 4) void kFused(
        const float* __restrict__ inp, const int* __restrict__ mask,
        const unsigned short* __restrict__ PTbf, const float* __restrict__ hd,
        const float* __restrict__ ev,
        float* __restrict__ partial, float2* __restrict__ zdm) {
    __shared__ __align__(16) unsigned short xs[32 * XST];   // 33280 B, live to the end
    __shared__ __align__(16) float w0f[32 * WST];           // 4608 B
    __shared__ float cs[32];                  // m * exp(v)  (unnormalized coeff)
    __shared__ float es[32];                  // exp(v)      (for Z)
    __shared__ float msk[32];                 // row mask as float

    const int tid = threadIdx.x;
    const int blk = blockIdx.x;
    const int rowBase = blk * 32;

    // ---- preload mask for this tile (overlaps with staging loads) ----
    if (tid < 32) msk[tid] = (mask[rowBase + tid] != 0) ? 1.0f : 0.0f;

    // ---- stage x tile (32 rows x 512 fp32 = 64 KB) -> LDS bf16, coalesced ----
    const float4* g = (const float4*)inp + (size_t)rowBase * 128;
    float4 tmp[16];
    #pragma unroll
    for (int i = 0; i < 16; ++i)
        tmp[i] = g[i * 256 + tid];            // flat index == row*128 + kq
    #pragma unroll
    for (int i = 0; i < 16; ++i) {
        int fi = i * 256 + tid;
        int row = fi >> 7, kq = fi & 127;
        unsigned p0, p1;                      // HW RNE pack: {lo=bf16(a), hi=bf16(b)}
        asm("v_cvt_pk_bf16_f32 %0, %1, %2" : "=v"(p0) : "v"(tmp[i].x), "v"(tmp[i].y));
        asm("v_cvt_pk_bf16_f32 %0, %1, %2" : "=v"(p1) : "v"(tmp[i].z), "v"(tmp[i].w));
        uint2 u; u.x = p0; u.y = p1;
        *(uint2*)(xs + row * XST + kq * 4) = u;
    }
    __syncthreads();

    // ---- MFMA: each wave one 16x16 tile (rowtile rt, coltile ct) ----
    const int wave = tid >> 6, lane = tid & 63;
    const int rt = wave & 1, ct = wave >> 1;
    const int m = lane & 15, quad = lane >> 4;

    const unsigned short* arow = xs + (rt * 16 + m) * XST + quad * 8;
    const unsigned short* brow = PTbf + (size_t)(ct * 16 + m) * 512 + quad * 8;

    f32x4 acc = {0.f, 0.f, 0.f, 0.f};
    #pragma unroll
    for (int ks = 0; ks < 16; ++ks) {
        s16x8 a = *(const s16x8*)(arow + ks * 32);
        s16x8 b = *(const s16x8*)(brow + ks * 32);
        acc = __builtin_amdgcn_mfma_f32_16x16x32_bf16(a, b, acc, 0, 0, 0);
    }

    // ---- epilogue: sigmoid(mask * score / sqrt(32)) -> w0f ----
    // C/D layout: col = lane&15, row = quad*4 + reg
    #pragma unroll
    for (int r = 0; r < 4; ++r) {
        int rowL = rt * 16 + quad * 4 + r;
        w0f[rowL * WST + ct * 16 + m] = sigmoidf_(msk[rowL] * acc[r] * INV_SCALE);
    }
    __syncthreads();

    // ---- hidden layer + evaluator fused, all 256 threads busy ----
    // thread (k = tid&31, slot = tid>>5) computes w1[row][k] for rows slot+8t,
    // multiplies by ev[k], shuffle-reduces over the 32-lane k-group.
    {
        const int k = tid & 31, slot = tid >> 5;
        const float evk = ev[k];
        float hdv[32];
        #pragma unroll
        for (int j = 0; j < 32; ++j) hdv[j] = hd[j * 32 + k];   // hd column k

        #pragma unroll
        for (int t = 0; t < 4; ++t) {
            const int row = slot + 8 * t;
            const float4* wr = (const float4*)(w0f + row * WST); // broadcast reads
            float s = 0.f;
            #pragma unroll
            for (int i = 0; i < 8; ++i) {
                float4 w4 = wr[i];
                s = fmaf(w4.x, hdv[4 * i + 0], s);
                s = fmaf(w4.y, hdv[4 * i + 1], s);
                s = fmaf(w4.z, hdv[4 * i + 2], s);
                s = fmaf(w4.w, hdv[4 * i + 3], s);
            }
            float val = sigmoidf_(s * INV_SCALE) * evk;   // w1[row][k] * ev[k]
            #pragma unroll
            for (int o = 1; o < 32; o <<= 1)              // sum over k (32-lane group)
                val += __shfl_xor(val, o);
            if (k == 0) {
                float v2 = sigmoidf_(val * INV_SCALE);    // in (0,1): exp safe
                float e  = __expf(v2);
                es[row] = e;
                cs[row] = msk[row] * e;
            }
        }
    }
    __syncthreads();

    // ---- block (Z, DM) partial: wave 0 only, overlapped with numerator ----
    if (tid < 64) {
        float z = 0.f, dm = 0.f;
        if (tid < 32) { z = es[tid]; dm = cs[tid]; }
        #pragma unroll
        for (int o = 32; o > 0; o >>= 1) {
            z  += __shfl_down(z, o);
            dm += __shfl_down(dm, o);
        }
        if (tid == 0) zdm[blk] = make_float2(z, dm);
    }

    // ---- numerator partial: thread owns d = {2*tid, 2*tid+1} ----
    float a0 = 0.f, a1 = 0.f;
    #pragma unroll 8
    for (int row = 0; row < 32; ++row) {
        unsigned u = *(const unsigned*)(xs + row * XST + 2 * tid); // conflict-free
        float x0 = __uint_as_float(u << 16);           // element 2*tid
        float x1 = __uint_as_float(u & 0xffff0000u);   // element 2*tid+1
        float c = cs[row];                              // broadcast
        a0 = fmaf(c, x0, a0);
        a1 = fmaf(c, x1, a1);
    }
    ((float2*)(partial + (size_t)blk * 512))[tid] = make_float2(a0, a1);
}

// ---- reduce 64 partials per b, normalize, write out ----
__global__ __launch_bounds__(256) void kReduce(
        const float* __restrict__ partial, const float2* __restrict__ zdm,
        float* __restrict__ out) {
    const int b = blockIdx.x, tid = threadIdx.x;
    __shared__ float sInv;

    if (tid < 64) {
        float2 p = zdm[b * 64 + tid];
        float z = p.x, dm = p.y;
        #pragma unroll
        for (int o = 32; o > 0; o >>= 1) {
            z  += __shfl_down(z, o);
            dm += __shfl_down(dm, o);
        }
        if (tid == 0) sInv = 1.0f / (dm + 1e-12f * z);
    }
    __syncthreads();

    const float2* pp = (const float2*)partial + (size_t)b * 64 * 256 + tid;
    float a0 = 0.f, b0 = 0.f, a1 = 0.f, b1 = 0.f;
    float a2 = 0.f, b2 = 0.f, a3 = 0.f, b3 = 0.f;
    #pragma unroll
    for (int i = 0; i < 64; i += 4) {          // 4 loads in flight
        float2 p0 = pp[(size_t)(i + 0) * 256];
        float2 p1 = pp[(size_t)(i + 1) * 256];
        float2 p2 = pp[(size_t)(i + 2) * 256];
        float2 p3 = pp[(size_t)(i + 3) * 256];
        a0 += p0.x; b0 += p0.y; a1 += p1.x; b1 += p1.y;
        a2 += p2.x; b2 += p2.y; a3 += p3.x; b3 += p3.y;
    }
    const float inv = sInv;
    float2 r;
    r.x = ((a0 + a1) + (a2 + a3)) * inv;
    r.y = ((b0 + b1) + (b2 + b3)) * inv;
    ((float2*)out)[b * 256 + tid] = r;
}

extern "C" void kernel_launch(void* const* d_in, const int* in_sizes, int n_in,
                              void* d_out, int out_size, void* d_ws, size_t ws_size,
                              hipStream_t stream) {
    const float* inp  = (const float*)d_in[0];
    const int*   mask = (const int*)d_in[1];
    const float* proj = (const float*)d_in[2];
    const float* hid  = (const float*)d_in[3];   // [1][32][32]
    const float* ev   = (const float*)d_in[4];   // [32]
    float* out = (float*)d_out;

    unsigned short* PTbf = (unsigned short*)d_ws;
    float2* zdm     = (float2*)((char*)d_ws + 32768);
    float*  partial = (float*)((char*)d_ws + 49152);

    kTransposeBf<<<64, 256, 0, stream>>>(proj, PTbf);
    kFused      <<<BS_ / 32, 256, 0, stream>>>(inp, mask, PTbf, hid, ev, partial, zdm);
    kReduce     <<<B_, 256, 0, stream>>>(partial, zdm, out);
}

// Round 3
// 207.936 us; speedup vs baseline: 1.0582x; 1.0281x over previous
//
#include <hip/hip_runtime.h>

// NOTE: resubmission of the round-2 pipelined kernel — previous bench died on
// container acquire (infra flake), not on kernel correctness.

#define B_   32
#define S_   2048
#define D_   512
#define H_   32
#define BS_  (B_*S_)
#define NTILE_ (BS_/32)          // 2048 tiles of 32 rows
#define TPB_   4                 // tiles per block (pipelined)
#define GRID_  (NTILE_/TPB_)     // 512 blocks = 2 per CU
#define INV_SCALE 0.17677669529663689f   // 1/sqrt(32)

// workspace layout (bytes):
// [0, 32768):            PTbf    ushort[32][512]   bf16 transposed projector
// [32768, 49152):        zdm     float2[2048]      per-tile (Z, DM) partials
// [49152, 4243456):      partial float[2048][512]  per-tile numerator partials

typedef short  s16x8 __attribute__((ext_vector_type(8)));
typedef float  f32x4 __attribute__((ext_vector_type(4)));

__device__ __forceinline__ float sigmoidf_(float x) {
    return 1.0f / (1.0f + __expf(-x));
}

__device__ __forceinline__ unsigned short f2bf(float f) {
    unsigned u = __float_as_uint(f);
    u += 0x7fffu + ((u >> 16) & 1u);     // round-to-nearest-even
    return (unsigned short)(u >> 16);
}

// ---------------- transpose projector to bf16: PTbf[j][d] = bf16(P[d][j]) ----
__global__ void kTransposeBf(const float* __restrict__ P, unsigned short* __restrict__ PTbf) {
    int o = blockIdx.x * 256 + threadIdx.x;      // 16384 total
    int j = o >> 9, d = o & 511;
    PTbf[o] = f2bf(P[d * H_ + j]);
}

// ---- fused scores + unnormalized weighted partial sum ----
// Each block pipelines TPB_ tiles of 32 rows: global loads for tile t+1 are
// issued before the compute tail of tile t, so HBM traffic never pauses.
#define XST 520                               // bf16 row stride in LDS (512 + 8 pad)
#define WST 36                                // w0f row stride (floats), 16B rows

__global__ __launch_bounds__(256, 2) void kFused(
        const float* __restrict__ inp, const int* __restrict__ mask,
        const unsigned short* __restrict__ PTbf, const float* __restrict__ hd,
        const float* __restrict__ ev,
        float* __restrict__ partial, float2* __restrict__ zdm) {
    __shared__ __align__(16) unsigned short xs[32 * XST];   // 33280 B, reused per tile
    __shared__ __align__(16) float w0f[32 * WST];           // 4608 B
    __shared__ float cs[32];                  // m * exp(v)  (unnormalized coeff)
    __shared__ float es[32];                  // exp(v)      (for Z)
    __shared__ float msk[32];                 // row mask as float

    const int tid = threadIdx.x;
    const int wave = tid >> 6, lane = tid & 63;
    const int rt = wave & 1, ct = wave >> 1;
    const int m = lane & 15, quad = lane >> 4;

    // ---- persistent per-block state (loaded once, reused for all tiles) ----
    // B fragments: 16 x s16x8 = 64 VGPRs
    s16x8 bf[16];
    {
        const unsigned short* brow = PTbf + (size_t)(ct * 16 + m) * 512 + quad * 8;
        #pragma unroll
        for (int ks = 0; ks < 16; ++ks)
            bf[ks] = *(const s16x8*)(brow + ks * 32);
    }
    // hidden-layer column k and evaluator weight: 33 VGPRs
    const int k = tid & 31, slot = tid >> 5;
    float hdv[32];
    #pragma unroll
    for (int j = 0; j < 32; ++j) hdv[j] = hd[j * 32 + k];
    const float evk = ev[k];

    const int tile0 = blockIdx.x * TPB_;

    // ---- issue loads for tile 0 (16 float4 per thread = 64 KiB/block) ----
    float4 tmp[16];
    {
        const float4* g = (const float4*)inp + (size_t)tile0 * 4096;
        #pragma unroll
        for (int i = 0; i < 16; ++i)
            tmp[i] = g[i * 256 + tid];        // flat index == row*128 + kq
    }

    for (int t = 0; t < TPB_; ++t) {
        const int tile = tile0 + t;
        const int rowBase = tile * 32;

        // ---- stage tile t: bf16 convert + LDS write (waits on tmp here) ----
        #pragma unroll
        for (int i = 0; i < 16; ++i) {
            int fi = i * 256 + tid;
            int row = fi >> 7, kq = fi & 127;
            unsigned p0, p1;                  // HW RNE pack
            asm("v_cvt_pk_bf16_f32 %0, %1, %2" : "=v"(p0) : "v"(tmp[i].x), "v"(tmp[i].y));
            asm("v_cvt_pk_bf16_f32 %0, %1, %2" : "=v"(p1) : "v"(tmp[i].z), "v"(tmp[i].w));
            uint2 u; u.x = p0; u.y = p1;
            *(uint2*)(xs + row * XST + kq * 4) = u;
        }
        if (tid < 32) msk[tid] = (mask[rowBase + tid] != 0) ? 1.0f : 0.0f;
        __syncthreads();

        // ---- prefetch tile t+1 into registers: in flight during whole tail ----
        if (t + 1 < TPB_) {
            const float4* g2 = (const float4*)inp + (size_t)(tile + 1) * 4096;
            #pragma unroll
            for (int i = 0; i < 16; ++i)
                tmp[i] = g2[i * 256 + tid];
        }

        // ---- MFMA: each wave one 16x16 tile (rowtile rt, coltile ct) ----
        const unsigned short* arow = xs + (rt * 16 + m) * XST + quad * 8;
        f32x4 acc = {0.f, 0.f, 0.f, 0.f};
        #pragma unroll
        for (int ks = 0; ks < 16; ++ks) {
            s16x8 a = *(const s16x8*)(arow + ks * 32);
            acc = __builtin_amdgcn_mfma_f32_16x16x32_bf16(a, bf[ks], acc, 0, 0, 0);
        }

        // epilogue: sigmoid(mask * score / sqrt(32)) -> w0f
        // C/D layout: col = lane&15, row = quad*4 + reg
        #pragma unroll
        for (int r = 0; r < 4; ++r) {
            int rowL = rt * 16 + quad * 4 + r;
            w0f[rowL * WST + ct * 16 + m] = sigmoidf_(msk[rowL] * acc[r] * INV_SCALE);
        }
        __syncthreads();

        // ---- hidden layer + evaluator fused, all 256 threads busy ----
        #pragma unroll
        for (int tt = 0; tt < 4; ++tt) {
            const int row = slot + 8 * tt;
            const float4* wr = (const float4*)(w0f + row * WST); // broadcast reads
            float s = 0.f;
            #pragma unroll
            for (int i = 0; i < 8; ++i) {
                float4 w4 = wr[i];
                s = fmaf(w4.x, hdv[4 * i + 0], s);
                s = fmaf(w4.y, hdv[4 * i + 1], s);
                s = fmaf(w4.z, hdv[4 * i + 2], s);
                s = fmaf(w4.w, hdv[4 * i + 3], s);
            }
            float val = sigmoidf_(s * INV_SCALE) * evk;   // w1[row][k] * ev[k]
            #pragma unroll
            for (int o = 1; o < 32; o <<= 1)              // sum over k (32-lane group)
                val += __shfl_xor(val, o);
            if (k == 0) {
                float v2 = sigmoidf_(val * INV_SCALE);    // in (0,1): exp safe
                float e  = __expf(v2);
                es[row] = e;
                cs[row] = msk[row] * e;
            }
        }
        __syncthreads();

        // ---- tile (Z, DM) partial: wave 0 only, overlapped with numerator ----
        if (tid < 64) {
            float z = 0.f, dm = 0.f;
            if (tid < 32) { z = es[tid]; dm = cs[tid]; }
            #pragma unroll
            for (int o = 32; o > 0; o >>= 1) {
                z  += __shfl_down(z, o);
                dm += __shfl_down(dm, o);
            }
            if (tid == 0) zdm[tile] = make_float2(z, dm);
        }

        // ---- numerator partial: thread owns d = {2*tid, 2*tid+1} ----
        float a0 = 0.f, a1 = 0.f;
        #pragma unroll 8
        for (int row = 0; row < 32; ++row) {
            unsigned u = *(const unsigned*)(xs + row * XST + 2 * tid); // conflict-free
            float x0 = __uint_as_float(u << 16);           // element 2*tid
            float x1 = __uint_as_float(u & 0xffff0000u);   // element 2*tid+1
            float c = cs[row];                              // broadcast
            a0 = fmaf(c, x0, a0);
            a1 = fmaf(c, x1, a1);
        }
        ((float2*)(partial + (size_t)tile * 512))[tid] = make_float2(a0, a1);

        __syncthreads();   // all xs reads done before next tile's stage overwrites
    }
}

// ---- reduce 64 partials per b, normalize, write out ----
__global__ __launch_bounds__(256) void kReduce(
        const float* __restrict__ partial, const float2* __restrict__ zdm,
        float* __restrict__ out) {
    const int b = blockIdx.x, tid = threadIdx.x;
    __shared__ float sInv;

    if (tid < 64) {
        float2 p = zdm[b * 64 + tid];
        float z = p.x, dm = p.y;
        #pragma unroll
        for (int o = 32; o > 0; o >>= 1) {
            z  += __shfl_down(z, o);
            dm += __shfl_down(dm, o);
        }
        if (tid == 0) sInv = 1.0f / (dm + 1e-12f * z);
    }
    __syncthreads();

    const float2* pp = (const float2*)partial + (size_t)b * 64 * 256 + tid;
    float a0 = 0.f, b0 = 0.f, a1 = 0.f, b1 = 0.f;
    float a2 = 0.f, b2 = 0.f, a3 = 0.f, b3 = 0.f;
    #pragma unroll
    for (int i = 0; i < 64; i += 4) {          // 4 loads in flight
        float2 p0 = pp[(size_t)(i + 0) * 256];
        float2 p1 = pp[(size_t)(i + 1) * 256];
        float2 p2 = pp[(size_t)(i + 2) * 256];
        float2 p3 = pp[(size_t)(i + 3) * 256];
        a0 += p0.x; b0 += p0.y; a1 += p1.x; b1 += p1.y;
        a2 += p2.x; b2 += p2.y; a3 += p3.x; b3 += p3.y;
    }
    const float inv = sInv;
    float2 r;
    r.x = ((a0 + a1) + (a2 + a3)) * inv;
    r.y = ((b0 + b1) + (b2 + b3)) * inv;
    ((float2*)out)[b * 256 + tid] = r;
}

extern "C" void kernel_launch(void* const* d_in, const int* in_sizes, int n_in,
                              void* d_out, int out_size, void* d_ws, size_t ws_size,
                              hipStream_t stream) {
    const float* inp  = (const float*)d_in[0];
    const int*   mask = (const int*)d_in[1];
    const float* proj = (const float*)d_in[2];
    const float* hid  = (const float*)d_in[3];   // [1][32][32]
    const float* ev   = (const float*)d_in[4];   // [32]
    float* out = (float*)d_out;

    unsigned short* PTbf = (unsigned short*)d_ws;
    float2* zdm     = (float2*)((char*)d_ws + 32768);
    float*  partial = (float*)((char*)d_ws + 49152);

    kTransposeBf<<<64, 256, 0, stream>>>(proj, PTbf);
    kFused      <<<GRID_, 256, 0, stream>>>(inp, mask, PTbf, hid, ev, partial, zdm);
    kReduce     <<<B_, 256, 0, stream>>>(partial, zdm, out);
}

// Round 4
// 206.989 us; speedup vs baseline: 1.0630x; 1.0046x over previous
//
#include <hip/hip_runtime.h>

#define B_   32
#define S_   2048
#define D_   512
#define H_   32
#define BS_  (B_*S_)
#define NTILE_ (BS_/32)          // 2048 tiles of 32 rows
#define TPB_   4                 // tiles per block (pipelined)
#define GRID_  (NTILE_/TPB_)     // 512 blocks = 2 per CU
#define INV_SCALE 0.17677669529663689f   // 1/sqrt(32)

// workspace layout (bytes):
// [0, 32768):            PTbf    ushort[32][512]   bf16 transposed projector
// [32768, 49152):        zdm     float2[2048]      per-tile (Z, DM) partials
// [49152, 4243456):      partial float[2048][512]  per-tile numerator partials

typedef short  s16x8 __attribute__((ext_vector_type(8)));
typedef float  f32x4 __attribute__((ext_vector_type(4)));

__device__ __forceinline__ float sigmoidf_(float x) {
    return 1.0f / (1.0f + __expf(-x));
}

__device__ __forceinline__ unsigned short f2bf(float f) {
    unsigned u = __float_as_uint(f);
    u += 0x7fffu + ((u >> 16) & 1u);     // round-to-nearest-even
    return (unsigned short)(u >> 16);
}

// LDS-ordering barrier that does NOT drain vmcnt.
// __syncthreads() emits `s_waitcnt vmcnt(0) lgkmcnt(0)` before s_barrier,
// killing any cross-barrier global-load prefetch. This variant orders LDS
// traffic only (lgkmcnt(0) covers all ds_write/ds_read completion); the
// register-destined prefetch loads stay in flight across it, and the
// compiler's dataflow inserts incremental vmcnt(N) waits at first use.
__device__ __forceinline__ void barrier_lds() {
    asm volatile("s_waitcnt lgkmcnt(0)" ::: "memory");
    __builtin_amdgcn_s_barrier();
    asm volatile("" ::: "memory");       // no LDS op hoists above the barrier
}

// ---------------- transpose projector to bf16: PTbf[j][d] = bf16(P[d][j]) ----
__global__ void kTransposeBf(const float* __restrict__ P, unsigned short* __restrict__ PTbf) {
    int o = blockIdx.x * 256 + threadIdx.x;      // 16384 total
    int j = o >> 9, d = o & 511;
    PTbf[o] = f2bf(P[d * H_ + j]);
}

// ---- fused scores + unnormalized weighted partial sum ----
#define XST 520                               // bf16 row stride in LDS (512 + 8 pad)
#define WST 36                                // w0f row stride (floats), 16B rows

__global__ __launch_bounds__(256, 2) void kFused(
        const float* __restrict__ inp, const int* __restrict__ mask,
        const unsigned short* __restrict__ PTbf, const float* __restrict__ hd,
        const float* __restrict__ ev,
        float* __restrict__ partial, float2* __restrict__ zdm) {
    __shared__ __align__(16) unsigned short xs[32 * XST];   // 33280 B, reused per tile
    __shared__ __align__(16) float w0f[32 * WST];           // 4608 B
    __shared__ float cs[32];                  // m * exp(v)
    __shared__ float es[32];                  // exp(v)
    __shared__ float mskAll[TPB_ * 32];       // masks for all 4 tiles

    const int tid = threadIdx.x;
    const int wave = tid >> 6, lane = tid & 63;
    const int rt = wave & 1, ct = wave >> 1;
    const int m = lane & 15, quad = lane >> 4;
    const int tile0 = blockIdx.x * TPB_;

    // ---- persistent per-block state (loaded once, reused for all tiles) ----
    s16x8 bf[16];                                      // 64 VGPR
    {
        const unsigned short* brow = PTbf + (size_t)(ct * 16 + m) * 512 + quad * 8;
        #pragma unroll
        for (int ks = 0; ks < 16; ++ks)
            bf[ks] = *(const s16x8*)(brow + ks * 32);
    }
    const int k = tid & 31, slot = tid >> 5;
    float hdv[32];                                     // 32 VGPR
    #pragma unroll
    for (int j = 0; j < 32; ++j) hdv[j] = hd[j * 32 + k];
    const float evk = ev[k];
    if (tid < TPB_ * 32)
        mskAll[tid] = (mask[tile0 * 32 + tid] != 0) ? 1.0f : 0.0f;

    // ---- issue loads for tile 0 (16 float4 per thread = 64 KiB/block) ----
    float4 tmp[16];                                    // 64 VGPR
    {
        const float4* g = (const float4*)inp + (size_t)tile0 * 4096;
        #pragma unroll
        for (int i = 0; i < 16; ++i)
            tmp[i] = g[i * 256 + tid];                 // flat index == row*128 + kq
    }

    for (int t = 0; t < TPB_; ++t) {
        const int tile = tile0 + t;

        // ---- stage tile t: bf16 convert + LDS write (incremental vmcnt waits) ----
        #pragma unroll
        for (int i = 0; i < 16; ++i) {
            int fi = i * 256 + tid;
            int row = fi >> 7, kq = fi & 127;
            unsigned p0, p1;                  // HW RNE pack
            asm("v_cvt_pk_bf16_f32 %0, %1, %2" : "=v"(p0) : "v"(tmp[i].x), "v"(tmp[i].y));
            asm("v_cvt_pk_bf16_f32 %0, %1, %2" : "=v"(p1) : "v"(tmp[i].z), "v"(tmp[i].w));
            uint2 u; u.x = p0; u.y = p1;
            *(uint2*)(xs + row * XST + kq * 4) = u;
        }
        barrier_lds();                                  // (1) xs ready

        // ---- prefetch tile t+1: stays in flight across ALL tail barriers ----
        if (t + 1 < TPB_) {
            const float4* g2 = (const float4*)inp + (size_t)(tile + 1) * 4096;
            #pragma unroll
            for (int i = 0; i < 16; ++i)
                tmp[i] = g2[i * 256 + tid];
        }

        // ---- MFMA: each wave one 16x16 tile (rowtile rt, coltile ct) ----
        const unsigned short* arow = xs + (rt * 16 + m) * XST + quad * 8;
        f32x4 acc = {0.f, 0.f, 0.f, 0.f};
        #pragma unroll
        for (int ks = 0; ks < 16; ++ks) {
            s16x8 a = *(const s16x8*)(arow + ks * 32);
            acc = __builtin_amdgcn_mfma_f32_16x16x32_bf16(a, bf[ks], acc, 0, 0, 0);
        }

        // epilogue: sigmoid(mask * score / sqrt(32)) -> w0f
        // C/D layout: col = lane&15, row = quad*4 + reg
        #pragma unroll
        for (int r = 0; r < 4; ++r) {
            int rowL = rt * 16 + quad * 4 + r;
            w0f[rowL * WST + ct * 16 + m] =
                sigmoidf_(mskAll[t * 32 + rowL] * acc[r] * INV_SCALE);
        }
        barrier_lds();                                  // (2) w0f ready

        // ---- hidden layer + evaluator fused, all 256 threads busy ----
        #pragma unroll
        for (int tt = 0; tt < 4; ++tt) {
            const int row = slot + 8 * tt;
            const float4* wr = (const float4*)(w0f + row * WST); // broadcast reads
            float s = 0.f;
            #pragma unroll
            for (int i = 0; i < 8; ++i) {
                float4 w4 = wr[i];
                s = fmaf(w4.x, hdv[4 * i + 0], s);
                s = fmaf(w4.y, hdv[4 * i + 1], s);
                s = fmaf(w4.z, hdv[4 * i + 2], s);
                s = fmaf(w4.w, hdv[4 * i + 3], s);
            }
            float val = sigmoidf_(s * INV_SCALE) * evk;   // w1[row][k] * ev[k]
            #pragma unroll
            for (int o = 1; o < 32; o <<= 1)              // sum over k (32-lane group)
                val += __shfl_xor(val, o);
            if (k == 0) {
                float v2 = sigmoidf_(val * INV_SCALE);    // in (0,1): exp safe
                float e  = __expf(v2);
                es[row] = e;
                cs[row] = mskAll[t * 32 + row] * e;
            }
        }
        barrier_lds();                                  // (3) cs/es ready

        // ---- tile (Z, DM) partial: wave 0 only ----
        if (tid < 64) {
            float z = 0.f, dm = 0.f;
            if (tid < 32) { z = es[tid]; dm = cs[tid]; }
            #pragma unroll
            for (int o = 32; o > 0; o >>= 1) {
                z  += __shfl_down(z, o);
                dm += __shfl_down(dm, o);
            }
            if (tid == 0) zdm[tile] = make_float2(z, dm);
        }

        // ---- numerator partial: thread owns d = {2*tid, 2*tid+1} ----
        float a0 = 0.f, a1 = 0.f;
        #pragma unroll 8
        for (int row = 0; row < 32; ++row) {
            unsigned u = *(const unsigned*)(xs + row * XST + 2 * tid); // conflict-free
            float x0 = __uint_as_float(u << 16);           // element 2*tid
            float x1 = __uint_as_float(u & 0xffff0000u);   // element 2*tid+1
            float c = cs[row];                              // broadcast
            a0 = fmaf(c, x0, a0);
            a1 = fmaf(c, x1, a1);
        }
        ((float2*)(partial + (size_t)tile * 512))[tid] = make_float2(a0, a1);

        barrier_lds();                                  // (4) xs reads done
    }
}

// ---- reduce 64 partials per b, normalize, write out ----
// 1024 threads: 4 groups of 256; each group sums 16 tiles with all 16 loads
// in flight, then LDS combine. Removes the old 64-batch latency chain.
__global__ __launch_bounds__(1024) void kReduce(
        const float* __restrict__ partial, const float2* __restrict__ zdm,
        float* __restrict__ out) {
    const int b = blockIdx.x, tid = threadIdx.x;
    const int d2 = tid & 255;            // float2 column (2 d per thread)
    const int g  = tid >> 8;             // tile-group 0..3
    __shared__ float sInv;
    __shared__ float2 red[3][256];

    if (tid < 64) {
        float2 p = zdm[b * 64 + tid];
        float z = p.x, dm = p.y;
        #pragma unroll
        for (int o = 32; o > 0; o >>= 1) {
            z  += __shfl_down(z, o);
            dm += __shfl_down(dm, o);
        }
        if (tid == 0) sInv = 1.0f / (dm + 1e-12f * z);
    }

    const float2* pp = (const float2*)partial + (size_t)b * 64 * 256 + d2;
    float2 v[16];
    #pragma unroll
    for (int j = 0; j < 16; ++j)                     // 16 loads in flight
        v[j] = pp[(size_t)(g * 16 + j) * 256];
    float a = 0.f, c = 0.f;
    #pragma unroll
    for (int j = 0; j < 16; ++j) { a += v[j].x; c += v[j].y; }

    if (g) red[g - 1][d2] = make_float2(a, c);
    __syncthreads();
    if (g == 0) {
        #pragma unroll
        for (int q = 0; q < 3; ++q) { a += red[q][d2].x; c += red[q][d2].y; }
        const float inv = sInv;
        ((float2*)out)[b * 256 + d2] = make_float2(a * inv, c * inv);
    }
}

extern "C" void kernel_launch(void* const* d_in, const int* in_sizes, int n_in,
                              void* d_out, int out_size, void* d_ws, size_t ws_size,
                              hipStream_t stream) {
    const float* inp  = (const float*)d_in[0];
    const int*   mask = (const int*)d_in[1];
    const float* proj = (const float*)d_in[2];
    const float* hid  = (const float*)d_in[3];   // [1][32][32]
    const float* ev   = (const float*)d_in[4];   // [32]
    float* out = (float*)d_out;

    unsigned short* PTbf = (unsigned short*)d_ws;
    float2* zdm     = (float2*)((char*)d_ws + 32768);
    float*  partial = (float*)((char*)d_ws + 49152);

    kTransposeBf<<<64, 256, 0, stream>>>(proj, PTbf);
    kFused      <<<GRID_, 256, 0, stream>>>(inp, mask, PTbf, hid, ev, partial, zdm);
    kReduce     <<<B_, 1024, 0, stream>>>(partial, zdm, out);
}